// Round 8
// baseline (279.924 us; speedup 1.0000x reference)
//
#include <hip/hip_runtime.h>
#include <hip/hip_bf16.h>
#include <math.h>

namespace {
constexpr int EDIM  = 512;
constexpr int DDIM  = 1024;
constexpr int ADIM  = 128;
constexpr int FDIM  = 32;
constexpr int KW    = 31;
constexpr int BATCH = 128;
constexpr int TDIM  = 512;

typedef __attribute__((ext_vector_type(8))) short short8;
typedef __attribute__((ext_vector_type(4))) float floatx4;

__device__ __forceinline__ float fast_tanh(float x) {
  x = fminf(9.0f, fmaxf(-9.0f, x));
  float e = __expf(2.0f * x);
  return (e - 1.0f) / (e + 1.0f);
}

__device__ __forceinline__ ushort2 pack_bf16(float x, float y) {
  union { __hip_bfloat162 h; ushort2 u; } cv;
  cv.h = __float22bfloat162_rn(make_float2(x, y));
  return cv.u;
}

__device__ __forceinline__ short8 pack8(floatx4 a, floatx4 b) {
  union { ushort2 u[4]; short8 v; } o;
  o.u[0] = pack_bf16(a[0], a[1]); o.u[1] = pack_bf16(a[2], a[3]);
  o.u[2] = pack_bf16(b[0], b[1]); o.u[3] = pack_bf16(b[2], b[3]);
  return o.v;
}

// dec_p[b,a] = sum_d dec[b,d] * Wdec[a,d]   grid (B, 4), 256 thr
__global__ __launch_bounds__(256)
void dec_proj_kernel(const float* __restrict__ dec,
                     const float* __restrict__ Wdec,
                     float* __restrict__ dec_p) {
  int b = blockIdx.x, az = blockIdx.y;
  int tid = threadIdx.x;
  int al = tid >> 3, seg = tid & 7;
  int a = az * 32 + al;
  const float* dv = dec + (size_t)b * DDIM;
  const float* wv = Wdec + (size_t)a * DDIM;
  float s = 0.f;
  #pragma unroll 8
  for (int it = 0; it < 32; ++it) {
    int d = it * 32 + seg * 4;
    float4 d4 = *(const float4*)(dv + d);
    float4 w4 = *(const float4*)(wv + d);
    s += d4.x * w4.x + d4.y * w4.y + d4.z * w4.z + d4.w * w4.w;
  }
  s += __shfl_xor(s, 1, 64);
  s += __shfl_xor(s, 2, 64);
  s += __shfl_xor(s, 4, 64);
  if (seg == 0) dec_p[b * ADIM + a] = s;
}

// ---------------- energies v8: R7 structure at 4 blocks/CU -----------------
// BM=64 -> grid 1024 (4 blocks/CU, vs R7's 2). Wave = 16 t-rows x 128 a's.
// enc A-fragments straight from global (depth-1 register prefetch, no
// barrier); Wenc staged in 4 K-quarters (32 KB LDS, chunk-XOR layout,
// verified zero-conflict R6/R7); loc_p = final MFMA round. 8 barriers/block;
// barrier drains overlap across the 4 co-resident blocks.
__global__ __launch_bounds__(256)
void energies_kernel(const float* __restrict__ enc,     // [B,T,E] fp32
                     const float* __restrict__ Wenc,    // [A,E] fp32
                     const float* __restrict__ pa,      // [B,T]
                     const float* __restrict__ convw,   // [F,1,K]
                     const float* __restrict__ Wloc,    // [A,F]
                     const float* __restrict__ We,      // [A]
                     const float* __restrict__ be,      // [1]
                     const float* __restrict__ dec_p,   // [B,A]
                     float* __restrict__ energ) {       // [B,T]
  __shared__ ushort WencS[16384];   // 32 KB: [sup(2)][row(128)][chunk(8)*8]
  __shared__ ushort convS[2048];    // 4 KB:  [t_local(64)][f(32)]
  __shared__ float pa_s[96];
  __shared__ float cw_s[FDIM * 33];

  const int tid  = threadIdx.x;
  const int b    = blockIdx.y;
  const int t0b  = blockIdx.x * 64;
  const int wave = tid >> 6, lane = tid & 63;
  const int lc = lane & 15, lq = lane >> 4;
  const int sw = lc & 7;

  if (tid < 94) {
    int gt = t0b - 15 + tid;
    pa_s[tid] = (gt >= 0 && gt < TDIM) ? pa[b * TDIM + gt] : 0.f;
  }
  for (int id = tid; id < FDIM * KW; id += 256)
    cw_s[(id / KW) * 33 + (id % KW)] = convw[id];
  __syncthreads();

  // conv(prev_attn) once per block: thread -> (t_local = tid>>2, 8 f's)
  {
    const int tl = tid >> 2, fg = tid & 3;
    float cv[8];
    #pragma unroll
    for (int n = 0; n < 8; ++n) {
      int f = fg * 8 + n;
      float s = 0.f;
      #pragma unroll
      for (int k = 0; k < KW; ++k) s += pa_s[tl + k] * cw_s[f * 33 + k];
      cv[n] = s;
    }
    *(short8*)&convS[tl * 32 + fg * 8] =
        pack8((floatx4){cv[0], cv[1], cv[2], cv[3]},
              (floatx4){cv[4], cv[5], cv[6], cv[7]});
  }

  // stage Wenc K-quarter 0 (2 super-tiles of BK=64; chunk c at pos c^(row&7))
  #pragma unroll
  for (int r = 0; r < 8; ++r) {
    int idx = tid + r * 256;
    int sup = idx >> 10, i2 = idx & 1023;
    int row = i2 >> 3, gc = (i2 & 7) ^ (row & 7);
    const float* g = Wenc + (size_t)row * EDIM + sup * 64 + gc * 8;
    *(short8*)&WencS[sup * 8192 + i2 * 8] =
        pack8(*(const floatx4*)g, *(const floatx4*)(g + 4));
  }

  // A-stream pointer + prefetch step 0 (wave strip = 16 rows)
  const float* pA = enc + ((size_t)(b * TDIM + t0b + wave * 16 + lc)) * EDIM + lq * 8;
  floatx4 ca = *(const floatx4*)pA, cb = *(const floatx4*)(pA + 4);

  float dpv[8], wev[8];
  #pragma unroll
  for (int aT = 0; aT < 8; ++aT) {
    int a = aT * 16 + lc;
    dpv[aT] = dec_p[b * ADIM + a];
    wev[aT] = We[a];
  }

  floatx4 acc[8];
  #pragma unroll
  for (int aT = 0; aT < 8; ++aT) acc[aT] = (floatx4){0.f, 0.f, 0.f, 0.f};

  __syncthreads();   // convS + WencS(quarter 0) visible

  for (int ph = 0; ph < 4; ++ph) {
    if (ph) {
      __syncthreads();   // quarter ph-1 readers done
      #pragma unroll
      for (int r = 0; r < 8; ++r) {
        int idx = tid + r * 256;
        int sup = idx >> 10, i2 = idx & 1023;
        int row = i2 >> 3, gc = (i2 & 7) ^ (row & 7);
        const float* g = Wenc + (size_t)row * EDIM + ph * 128 + sup * 64 + gc * 8;
        *(short8*)&WencS[sup * 8192 + i2 * 8] =
            pack8(*(const floatx4*)g, *(const floatx4*)(g + 4));
      }
      __syncthreads();   // quarter ph visible
    }
    #pragma unroll
    for (int st = 0; st < 4; ++st) {
      const int step = ph * 4 + st;
      floatx4 na = {0,0,0,0}, nb = {0,0,0,0};
      if (step < 15) {
        const float* q = pA + (step + 1) * 32;
        na = *(const floatx4*)q; nb = *(const floatx4*)(q + 4);
      }
      short8 af = pack8(ca, cb);
      const int cco = (((st & 1) * 4 + lq) ^ sw) * 8;
      const ushort* Bb = &WencS[(st >> 1) * 8192 + cco];
      #pragma unroll
      for (int aT = 0; aT < 8; ++aT) {
        short8 bf = *(const short8*)&Bb[(aT * 16 + lc) * 64];
        acc[aT] = __builtin_amdgcn_mfma_f32_16x16x32_bf16(af, bf, acc[aT], 0, 0, 0);
      }
      ca = na; cb = nb;
    }
  }

  // loc round: A = conv tile (convS), B = Wloc from global (L1/L2-hot), K=32
  {
    short8 afl = *(const short8*)&convS[(wave * 16 + lc) * 32 + lq * 8];
    #pragma unroll
    for (int aT = 0; aT < 8; ++aT) {
      const float* g = Wloc + (size_t)(aT * 16 + lc) * FDIM + lq * 8;
      short8 bfl = pack8(*(const floatx4*)g, *(const floatx4*)(g + 4));
      acc[aT] = __builtin_amdgcn_mfma_f32_16x16x32_bf16(afl, bfl, acc[aT], 0, 0, 0);
    }
  }

  // epilogue (within-wave): e[t] = sum_a tanh(x + dp)*We + be
  const float be0 = be[0];
  {
    float es[4] = {0.f, 0.f, 0.f, 0.f};
    #pragma unroll
    for (int aT = 0; aT < 8; ++aT)
      #pragma unroll
      for (int i = 0; i < 4; ++i)
        es[i] += fast_tanh(acc[aT][i] + dpv[aT]) * wev[aT];
    #pragma unroll
    for (int m = 1; m < 16; m <<= 1)
      #pragma unroll
      for (int i = 0; i < 4; ++i) es[i] += __shfl_xor(es[i], m, 64);
    if (lc == 0) {
      floatx4 ev = {es[0] + be0, es[1] + be0, es[2] + be0, es[3] + be0};
      *(floatx4*)&energ[(size_t)b * TDIM + t0b + wave * 16 + lq * 4] = ev;
    }
  }
}

// ---- fused softmax + context: grid (4 e-chunks of 128, B), 256 thr --------
__global__ __launch_bounds__(256)
void softmax_context_kernel(const float* __restrict__ enc,
                            const float* __restrict__ energ,
                            float* __restrict__ attn,
                            float* __restrict__ ctx) {
  __shared__ float aw[TDIM];
  __shared__ float redm[4];
  __shared__ float reds[4];
  __shared__ float red2[128];
  const int b = blockIdx.y, ex = blockIdx.x, tid = threadIdx.x;
  const float* row = energ + (size_t)b * TDIM;
  float x0 = row[tid], x1 = row[tid + 256];
  float m = fmaxf(x0, x1);
  #pragma unroll
  for (int off = 32; off; off >>= 1) m = fmaxf(m, __shfl_xor(m, off, 64));
  int wid = tid >> 6, lane = tid & 63;
  if (lane == 0) redm[wid] = m;
  __syncthreads();
  m = fmaxf(fmaxf(redm[0], redm[1]), fmaxf(redm[2], redm[3]));
  float e0 = __expf(x0 - m), e1 = __expf(x1 - m);
  float s = e0 + e1;
  #pragma unroll
  for (int off = 32; off; off >>= 1) s += __shfl_xor(s, off, 64);
  if (lane == 0) reds[wid] = s;
  __syncthreads();
  s = reds[0] + reds[1] + reds[2] + reds[3];
  float inv = 1.0f / s;
  float w0 = e0 * inv, w1 = e1 * inv;
  aw[tid] = w0; aw[tid + 256] = w1;
  if (ex == 0) {
    attn[(size_t)b * TDIM + tid] = w0;
    attn[(size_t)b * TDIM + tid + 256] = w1;
  }
  __syncthreads();
  const int j = tid & 127, h = tid >> 7;
  const float* ep = enc + ((size_t)(b * TDIM + h * 256)) * EDIM + ex * 128 + j;
  float acc = 0.f;
  #pragma unroll 16
  for (int t = 0; t < 256; ++t) acc += aw[h * 256 + t] * ep[(size_t)t * EDIM];
  if (h == 1) red2[j] = acc;
  __syncthreads();
  if (h == 0) ctx[(size_t)b * EDIM + ex * 128 + j] = acc + red2[j];
}

// In-place fallback (energies stored in attn slice): grid (1, B)
__global__ __launch_bounds__(256)
void softmax_context_inplace_kernel(const float* __restrict__ enc,
                                    float* __restrict__ attn,
                                    float* __restrict__ ctx) {
  __shared__ float aw[TDIM];
  __shared__ float redm[4];
  __shared__ float reds[4];
  const int b = blockIdx.y, tid = threadIdx.x;
  float* row = attn + (size_t)b * TDIM;
  float x0 = row[tid], x1 = row[tid + 256];
  float m = fmaxf(x0, x1);
  #pragma unroll
  for (int off = 32; off; off >>= 1) m = fmaxf(m, __shfl_xor(m, off, 64));
  int wid = tid >> 6, lane = tid & 63;
  if (lane == 0) redm[wid] = m;
  __syncthreads();
  m = fmaxf(fmaxf(redm[0], redm[1]), fmaxf(redm[2], redm[3]));
  float e0 = __expf(x0 - m), e1 = __expf(x1 - m);
  float s = e0 + e1;
  #pragma unroll
  for (int off = 32; off; off >>= 1) s += __shfl_xor(s, off, 64);
  if (lane == 0) reds[wid] = s;
  __syncthreads();
  s = reds[0] + reds[1] + reds[2] + reds[3];
  float inv = 1.0f / s;
  float w0 = e0 * inv, w1 = e1 * inv;
  row[tid] = w0; row[tid + 256] = w1;
  aw[tid] = w0; aw[tid + 256] = w1;
  __syncthreads();
  const float* ep = enc + ((size_t)b * TDIM) * EDIM;
  float a0 = 0.f, a1 = 0.f;
  #pragma unroll 8
  for (int t = 0; t < TDIM; ++t) {
    float w = aw[t];
    a0 += w * ep[(size_t)t * EDIM + tid];
    a1 += w * ep[(size_t)t * EDIM + tid + 256];
  }
  ctx[(size_t)b * EDIM + tid] = a0;
  ctx[(size_t)b * EDIM + tid + 256] = a1;
}

}  // namespace

extern "C" void kernel_launch(void* const* d_in, const int* in_sizes, int n_in,
                              void* d_out, int out_size, void* d_ws, size_t ws_size,
                              hipStream_t stream) {
  const float* enc   = (const float*)d_in[0];
  const float* dec   = (const float*)d_in[1];
  const float* pa    = (const float*)d_in[2];
  const float* Wenc  = (const float*)d_in[3];
  const float* Wdec  = (const float*)d_in[4];
  const float* convw = (const float*)d_in[5];
  const float* Wloc  = (const float*)d_in[6];
  const float* We    = (const float*)d_in[7];
  const float* be    = (const float*)d_in[8];

  float* ctx  = (float*)d_out;                 // [B,E]
  float* attn = (float*)d_out + BATCH * EDIM;  // [B,T]

  float* dec_p = (float*)d_ws;                 // 64 KB
  float* energ = dec_p + BATCH * ADIM;         // 256 KB

  const size_t need = (size_t)(BATCH * ADIM + BATCH * TDIM) * sizeof(float);

  dim3 g1(BATCH, 4);
  dec_proj_kernel<<<g1, 256, 0, stream>>>(dec, Wdec, dec_p);

  dim3 g2(TDIM / 64, BATCH);
  if (ws_size >= need) {
    energies_kernel<<<g2, 256, 0, stream>>>(enc, Wenc, pa, convw, Wloc, We, be,
                                            dec_p, energ);
    dim3 g3(4, BATCH);
    softmax_context_kernel<<<g3, 256, 0, stream>>>(enc, energ, attn, ctx);
  } else {
    energies_kernel<<<g2, 256, 0, stream>>>(enc, Wenc, pa, convw, Wloc, We, be,
                                            dec_p, attn);
    dim3 g3(1, BATCH);
    softmax_context_inplace_kernel<<<g3, 256, 0, stream>>>(enc, attn, ctx);
  }
}

// Round 9
// 245.905 us; speedup vs baseline: 1.1383x; 1.1383x over previous
//
#include <hip/hip_runtime.h>
#include <hip/hip_bf16.h>
#include <math.h>

namespace {
constexpr int EDIM  = 512;
constexpr int DDIM  = 1024;
constexpr int ADIM  = 128;
constexpr int FDIM  = 32;
constexpr int KW    = 31;
constexpr int BATCH = 128;
constexpr int TDIM  = 512;

constexpr int LSTR = 40;     // LDS row stride in ushorts (80 B -> 2-way banks, free)
constexpr int TILE = 128 * LSTR;  // one operand tile (5120 ushorts)

typedef __attribute__((ext_vector_type(8))) short short8;
typedef __attribute__((ext_vector_type(4))) float floatx4;

__device__ __forceinline__ float fast_tanh(float x) {
  x = fminf(9.0f, fmaxf(-9.0f, x));
  float e = __expf(2.0f * x);
  return (e - 1.0f) / (e + 1.0f);
}

__device__ __forceinline__ ushort2 pack_bf16(float x, float y) {
  union { __hip_bfloat162 h; ushort2 u; } cv;
  cv.h = __float22bfloat162_rn(make_float2(x, y));
  return cv.u;
}

__device__ __forceinline__ short8 pack8(floatx4 a, floatx4 b) {
  union { ushort2 u[4]; short8 v; } o;
  o.u[0] = pack_bf16(a[0], a[1]); o.u[1] = pack_bf16(a[2], a[3]);
  o.u[2] = pack_bf16(b[0], b[1]); o.u[3] = pack_bf16(b[2], b[3]);
  return o.v;
}

__device__ __forceinline__ int ld_acq(int* p) {
  return __hip_atomic_load(p, __ATOMIC_ACQUIRE, __HIP_MEMORY_SCOPE_WORKGROUP);
}
__device__ __forceinline__ void add_rel(int* p) {
  __hip_atomic_fetch_add(p, 1, __ATOMIC_RELEASE, __HIP_MEMORY_SCOPE_WORKGROUP);
}

// dec_p[b,a] = sum_d dec[b,d] * Wdec[a,d]   grid (B, 4), 256 thr
__global__ __launch_bounds__(256)
void dec_proj_kernel(const float* __restrict__ dec,
                     const float* __restrict__ Wdec,
                     float* __restrict__ dec_p) {
  int b = blockIdx.x, az = blockIdx.y;
  int tid = threadIdx.x;
  int al = tid >> 3, seg = tid & 7;
  int a = az * 32 + al;
  const float* dv = dec + (size_t)b * DDIM;
  const float* wv = Wdec + (size_t)a * DDIM;
  float s = 0.f;
  #pragma unroll 8
  for (int it = 0; it < 32; ++it) {
    int d = it * 32 + seg * 4;
    float4 d4 = *(const float4*)(dv + d);
    float4 w4 = *(const float4*)(wv + d);
    s += d4.x * w4.x + d4.y * w4.y + d4.z * w4.z + d4.w * w4.w;
  }
  s += __shfl_xor(s, 1, 64);
  s += __shfl_xor(s, 2, 64);
  s += __shfl_xor(s, 4, 64);
  if (seg == 0) dec_p[b * ADIM + a] = s;
}

// ------------- energies v9: producer-consumer wave specialization ----------
// 768 threads = 12 waves. Waves 0-7: consumers (16 t-rows x 128 a each).
// Waves 8-9: A-producers (enc, 64 rows each). Waves 10-11: B-producers
// (Wenc). 16 tiles of BK=32, 2 LDS slots, synchronized by LDS
// acquire/release atomics — NO __syncthreads in the K-loop, so consumer
// waves never wait on a vmcnt(0) drain; producer load stalls overlap
// consumer MFMA (separate waves, m114 co-scheduling).
__global__ __launch_bounds__(768)
void energies_kernel(const float* __restrict__ enc,     // [B,T,E] fp32
                     const float* __restrict__ Wenc,    // [A,E] fp32
                     const float* __restrict__ pa,      // [B,T]
                     const float* __restrict__ convw,   // [F,1,K]
                     const float* __restrict__ Wloc,    // [A,F]
                     const float* __restrict__ We,      // [A]
                     const float* __restrict__ be,      // [1]
                     const float* __restrict__ dec_p,   // [B,A]
                     float* __restrict__ energ) {       // [B,T]
  __shared__ ushort tiles[2 * 2 * TILE];   // [slot(2)][A|B][128][LSTR] 40 KB
  __shared__ ushort convS[4096];           // [t_local(128)][f(32)] 8 KB
  __shared__ float pa_s[160];
  __shared__ float cw_s[FDIM * 33];
  __shared__ int ready_a[2], ready_b[2], done_c[2], conv_done;

  const int tid  = threadIdx.x;
  const int b    = blockIdx.y;
  const int t0b  = blockIdx.x * 128;
  const int wave = tid >> 6, lane = tid & 63;

  if (tid == 0) {
    ready_a[0] = ready_a[1] = ready_b[0] = ready_b[1] = 0;
    done_c[0] = done_c[1] = 0;
    conv_done = 0;
  }
  if (tid >= 512 && tid < 512 + 158) {
    int gt = t0b - 15 + (tid - 512);
    pa_s[tid - 512] = (gt >= 0 && gt < TDIM) ? pa[b * TDIM + gt] : 0.f;
  }
  if (tid < 512)
    for (int id = tid; id < FDIM * KW; id += 512)
      cw_s[(id / KW) * 33 + (id % KW)] = convw[id];
  __syncthreads();   // the only barrier: flags zeroed, pa_s/cw_s staged

  if (wave >= 8) {
    // ---------------- producers ----------------
    const bool isA = (wave < 10);
    const int p = wave & 1;               // which half of the 128 rows
    const float* gbase = isA ? enc + ((size_t)(b * TDIM + t0b)) * EDIM : Wenc;
    ushort* lbase = tiles + (isA ? 0 : TILE);
    int* myready = isA ? ready_a : ready_b;
    for (int kt = 0; kt < 16; ++kt) {
      const int s = kt & 1, i = kt >> 1;
      if (kt >= 2)
        while (ld_acq(&done_c[s]) < 8 * i) __builtin_amdgcn_s_sleep(2);
      ushort* slot = lbase + s * 2 * TILE;
      floatx4 v[8];
      #pragma unroll
      for (int j = 0; j < 4; ++j) {
        int idx = j * 64 + lane;                  // 0..255
        int row = p * 64 + (idx >> 2), c = idx & 3;
        const float* g = gbase + (size_t)row * EDIM + kt * 32 + c * 8;
        v[2 * j]     = *(const floatx4*)g;
        v[2 * j + 1] = *(const floatx4*)(g + 4);
      }
      #pragma unroll
      for (int j = 0; j < 4; ++j) {
        int idx = j * 64 + lane;
        int row = p * 64 + (idx >> 2), c = idx & 3;
        *(short8*)&slot[row * LSTR + c * 8] = pack8(v[2 * j], v[2 * j + 1]);
      }
      __threadfence_block();
      if (lane == 0) add_rel(&myready[s]);
    }
    return;
  }

  // ---------------- consumers (waves 0-7) ----------------
  const int lc = lane & 15, lq = lane >> 4;

  // location conv -> convS (tid<512: tl spans all 128 rows)
  {
    const int tl = tid >> 2, fg = tid & 3;
    float cv[8];
    #pragma unroll
    for (int n = 0; n < 8; ++n) {
      int f = fg * 8 + n;
      float s = 0.f;
      #pragma unroll
      for (int k = 0; k < KW; ++k) s += pa_s[tl + k] * cw_s[f * 33 + k];
      cv[n] = s;
    }
    *(short8*)&convS[tl * 32 + fg * 8] =
        pack8((floatx4){cv[0], cv[1], cv[2], cv[3]},
              (floatx4){cv[4], cv[5], cv[6], cv[7]});
  }
  __threadfence_block();
  if (lane == 0) add_rel(&conv_done);

  floatx4 acc[8];
  #pragma unroll
  for (int aT = 0; aT < 8; ++aT) acc[aT] = (floatx4){0.f, 0.f, 0.f, 0.f};

  for (int kt = 0; kt < 16; ++kt) {
    const int s = kt & 1, i = kt >> 1;
    const int need = 2 * (i + 1);   // 2 producer waves per operand per tile
    while (ld_acq(&ready_a[s]) < need || ld_acq(&ready_b[s]) < need)
      __builtin_amdgcn_s_sleep(2);
    const ushort* As_ = tiles + s * 2 * TILE;
    const ushort* Bs_ = As_ + TILE;
    short8 af = *(const short8*)&As_[(wave * 16 + lc) * LSTR + lq * 8];
    #pragma unroll
    for (int aT = 0; aT < 8; ++aT) {
      short8 bf = *(const short8*)&Bs_[(aT * 16 + lc) * LSTR + lq * 8];
      acc[aT] = __builtin_amdgcn_mfma_f32_16x16x32_bf16(af, bf, acc[aT], 0, 0, 0);
    }
    if (lane == 0) add_rel(&done_c[s]);
  }

  // loc round: A = convS (needs all waves' conv writes), B = Wloc (global)
  while (ld_acq(&conv_done) < 8) __builtin_amdgcn_s_sleep(2);
  {
    short8 afl = *(const short8*)&convS[(wave * 16 + lc) * 32 + lq * 8];
    #pragma unroll
    for (int aT = 0; aT < 8; ++aT) {
      const float* g = Wloc + (size_t)(aT * 16 + lc) * FDIM + lq * 8;
      short8 bfl = pack8(*(const floatx4*)g, *(const floatx4*)(g + 4));
      acc[aT] = __builtin_amdgcn_mfma_f32_16x16x32_bf16(afl, bfl, acc[aT], 0, 0, 0);
    }
  }

  // epilogue (within-wave): e[t] = sum_a tanh(x + dp)*We + be
  const float be0 = be[0];
  float dpv[8], wev[8];
  #pragma unroll
  for (int aT = 0; aT < 8; ++aT) {
    int a = aT * 16 + lc;
    dpv[aT] = dec_p[b * ADIM + a];
    wev[aT] = We[a];
  }
  {
    float es[4] = {0.f, 0.f, 0.f, 0.f};
    #pragma unroll
    for (int aT = 0; aT < 8; ++aT)
      #pragma unroll
      for (int i = 0; i < 4; ++i)
        es[i] += fast_tanh(acc[aT][i] + dpv[aT]) * wev[aT];
    #pragma unroll
    for (int m = 1; m < 16; m <<= 1)
      #pragma unroll
      for (int i = 0; i < 4; ++i) es[i] += __shfl_xor(es[i], m, 64);
    if (lc == 0) {
      floatx4 ev = {es[0] + be0, es[1] + be0, es[2] + be0, es[3] + be0};
      *(floatx4*)&energ[(size_t)b * TDIM + t0b + wave * 16 + lq * 4] = ev;
    }
  }
}

// ---- fused softmax + context: grid (4 e-chunks of 128, B), 256 thr --------
__global__ __launch_bounds__(256)
void softmax_context_kernel(const float* __restrict__ enc,
                            const float* __restrict__ energ,
                            float* __restrict__ attn,
                            float* __restrict__ ctx) {
  __shared__ float aw[TDIM];
  __shared__ float redm[4];
  __shared__ float reds[4];
  __shared__ float red2[128];
  const int b = blockIdx.y, ex = blockIdx.x, tid = threadIdx.x;
  const float* row = energ + (size_t)b * TDIM;
  float x0 = row[tid], x1 = row[tid + 256];
  float m = fmaxf(x0, x1);
  #pragma unroll
  for (int off = 32; off; off >>= 1) m = fmaxf(m, __shfl_xor(m, off, 64));
  int wid = tid >> 6, lane = tid & 63;
  if (lane == 0) redm[wid] = m;
  __syncthreads();
  m = fmaxf(fmaxf(redm[0], redm[1]), fmaxf(redm[2], redm[3]));
  float e0 = __expf(x0 - m), e1 = __expf(x1 - m);
  float s = e0 + e1;
  #pragma unroll
  for (int off = 32; off; off >>= 1) s += __shfl_xor(s, off, 64);
  if (lane == 0) reds[wid] = s;
  __syncthreads();
  s = reds[0] + reds[1] + reds[2] + reds[3];
  float inv = 1.0f / s;
  float w0 = e0 * inv, w1 = e1 * inv;
  aw[tid] = w0; aw[tid + 256] = w1;
  if (ex == 0) {
    attn[(size_t)b * TDIM + tid] = w0;
    attn[(size_t)b * TDIM + tid + 256] = w1;
  }
  __syncthreads();
  const int j = tid & 127, h = tid >> 7;
  const float* ep = enc + ((size_t)(b * TDIM + h * 256)) * EDIM + ex * 128 + j;
  float acc = 0.f;
  #pragma unroll 16
  for (int t = 0; t < 256; ++t) acc += aw[h * 256 + t] * ep[(size_t)t * EDIM];
  if (h == 1) red2[j] = acc;
  __syncthreads();
  if (h == 0) ctx[(size_t)b * EDIM + ex * 128 + j] = acc + red2[j];
}

// In-place fallback (energies stored in attn slice): grid (1, B)
__global__ __launch_bounds__(256)
void softmax_context_inplace_kernel(const float* __restrict__ enc,
                                    float* __restrict__ attn,
                                    float* __restrict__ ctx) {
  __shared__ float aw[TDIM];
  __shared__ float redm[4];
  __shared__ float reds[4];
  const int b = blockIdx.y, tid = threadIdx.x;
  float* row = attn + (size_t)b * TDIM;
  float x0 = row[tid], x1 = row[tid + 256];
  float m = fmaxf(x0, x1);
  #pragma unroll
  for (int off = 32; off; off >>= 1) m = fmaxf(m, __shfl_xor(m, off, 64));
  int wid = tid >> 6, lane = tid & 63;
  if (lane == 0) redm[wid] = m;
  __syncthreads();
  m = fmaxf(fmaxf(redm[0], redm[1]), fmaxf(redm[2], redm[3]));
  float e0 = __expf(x0 - m), e1 = __expf(x1 - m);
  float s = e0 + e1;
  #pragma unroll
  for (int off = 32; off; off >>= 1) s += __shfl_xor(s, off, 64);
  if (lane == 0) reds[wid] = s;
  __syncthreads();
  s = reds[0] + reds[1] + reds[2] + reds[3];
  float inv = 1.0f / s;
  float w0 = e0 * inv, w1 = e1 * inv;
  row[tid] = w0; row[tid + 256] = w1;
  aw[tid] = w0; aw[tid + 256] = w1;
  __syncthreads();
  const float* ep = enc + ((size_t)b * TDIM) * EDIM;
  float a0 = 0.f, a1 = 0.f;
  #pragma unroll 8
  for (int t = 0; t < TDIM; ++t) {
    float w = aw[t];
    a0 += w * ep[(size_t)t * EDIM + tid];
    a1 += w * ep[(size_t)t * EDIM + tid + 256];
  }
  ctx[(size_t)b * EDIM + tid] = a0;
  ctx[(size_t)b * EDIM + tid + 256] = a1;
}

}  // namespace

extern "C" void kernel_launch(void* const* d_in, const int* in_sizes, int n_in,
                              void* d_out, int out_size, void* d_ws, size_t ws_size,
                              hipStream_t stream) {
  const float* enc   = (const float*)d_in[0];
  const float* dec   = (const float*)d_in[1];
  const float* pa    = (const float*)d_in[2];
  const float* Wenc  = (const float*)d_in[3];
  const float* Wdec  = (const float*)d_in[4];
  const float* convw = (const float*)d_in[5];
  const float* Wloc  = (const float*)d_in[6];
  const float* We    = (const float*)d_in[7];
  const float* be    = (const float*)d_in[8];

  float* ctx  = (float*)d_out;                 // [B,E]
  float* attn = (float*)d_out + BATCH * EDIM;  // [B,T]

  float* dec_p = (float*)d_ws;                 // 64 KB
  float* energ = dec_p + BATCH * ADIM;         // 256 KB

  const size_t need = (size_t)(BATCH * ADIM + BATCH * TDIM) * sizeof(float);

  dim3 g1(BATCH, 4);
  dec_proj_kernel<<<g1, 256, 0, stream>>>(dec, Wdec, dec_p);

  dim3 g2(TDIM / 128, BATCH);
  if (ws_size >= need) {
    energies_kernel<<<g2, 768, 0, stream>>>(enc, Wenc, pa, convw, Wloc, We, be,
                                            dec_p, energ);
    dim3 g3(4, BATCH);
    softmax_context_kernel<<<g3, 256, 0, stream>>>(enc, energ, attn, ctx);
  } else {
    energies_kernel<<<g2, 768, 0, stream>>>(enc, Wenc, pa, convw, Wloc, We, be,
                                            dec_p, attn);
    dim3 g3(1, BATCH);
    softmax_context_inplace_kernel<<<g3, 256, 0, stream>>>(enc, attn, ctx);
  }
}

// Round 10
// 245.133 us; speedup vs baseline: 1.1419x; 1.0032x over previous
//
#include <hip/hip_runtime.h>
#include <hip/hip_bf16.h>
#include <math.h>

namespace {
constexpr int EDIM  = 512;
constexpr int DDIM  = 1024;
constexpr int ADIM  = 128;
constexpr int FDIM  = 32;
constexpr int KW    = 31;
constexpr int BATCH = 128;
constexpr int TDIM  = 512;

constexpr int LSTR = 40;     // LDS row stride in ushorts (80 B -> 2-way banks, free)
constexpr int TILE = 128 * LSTR;  // one operand tile (5120 ushorts)

typedef __attribute__((ext_vector_type(8))) short short8;
typedef __attribute__((ext_vector_type(4))) float floatx4;

__device__ __forceinline__ float fast_tanh(float x) {
  x = fminf(9.0f, fmaxf(-9.0f, x));
  float e = __expf(2.0f * x);
  return (e - 1.0f) / (e + 1.0f);
}

__device__ __forceinline__ ushort2 pack_bf16(float x, float y) {
  union { __hip_bfloat162 h; ushort2 u; } cv;
  cv.h = __float22bfloat162_rn(make_float2(x, y));
  return cv.u;
}

__device__ __forceinline__ short8 pack8(floatx4 a, floatx4 b) {
  union { ushort2 u[4]; short8 v; } o;
  o.u[0] = pack_bf16(a[0], a[1]); o.u[1] = pack_bf16(a[2], a[3]);
  o.u[2] = pack_bf16(b[0], b[1]); o.u[3] = pack_bf16(b[2], b[3]);
  return o.v;
}

__device__ __forceinline__ int ld_acq(int* p) {
  return __hip_atomic_load(p, __ATOMIC_ACQUIRE, __HIP_MEMORY_SCOPE_WORKGROUP);
}
__device__ __forceinline__ void add_rel(int* p) {
  __hip_atomic_fetch_add(p, 1, __ATOMIC_RELEASE, __HIP_MEMORY_SCOPE_WORKGROUP);
}

// dec_p[b,a] = sum_d dec[b,d] * Wdec[a,d]   grid (B, 4), 256 thr
__global__ __launch_bounds__(256)
void dec_proj_kernel(const float* __restrict__ dec,
                     const float* __restrict__ Wdec,
                     float* __restrict__ dec_p) {
  int b = blockIdx.x, az = blockIdx.y;
  int tid = threadIdx.x;
  int al = tid >> 3, seg = tid & 7;
  int a = az * 32 + al;
  const float* dv = dec + (size_t)b * DDIM;
  const float* wv = Wdec + (size_t)a * DDIM;
  float s = 0.f;
  #pragma unroll 8
  for (int it = 0; it < 32; ++it) {
    int d = it * 32 + seg * 4;
    float4 d4 = *(const float4*)(dv + d);
    float4 w4 = *(const float4*)(wv + d);
    s += d4.x * w4.x + d4.y * w4.y + d4.z * w4.z + d4.w * w4.w;
  }
  s += __shfl_xor(s, 1, 64);
  s += __shfl_xor(s, 2, 64);
  s += __shfl_xor(s, 4, 64);
  if (seg == 0) dec_p[b * ADIM + a] = s;
}

// ------------- energies v10: producer-consumer + early producer loads ------
// R9 structure (12 waves: 8 consumers, 2 A-prod, 2 B-prod; 2 LDS slots;
// LDS-atomic flags, no K-loop __syncthreads). R10 change: producers issue
// the NEXT tile's global loads immediately after signaling the current tile
// (register-targeted, needs no free slot) so HBM latency flies during the
// done_c wait + consumer MFMA instead of being serially exposed per tile.
__global__ __launch_bounds__(768)
void energies_kernel(const float* __restrict__ enc,     // [B,T,E] fp32
                     const float* __restrict__ Wenc,    // [A,E] fp32
                     const float* __restrict__ pa,      // [B,T]
                     const float* __restrict__ convw,   // [F,1,K]
                     const float* __restrict__ Wloc,    // [A,F]
                     const float* __restrict__ We,      // [A]
                     const float* __restrict__ be,      // [1]
                     const float* __restrict__ dec_p,   // [B,A]
                     float* __restrict__ energ) {       // [B,T]
  __shared__ ushort tiles[2 * 2 * TILE];   // [slot(2)][A|B][128][LSTR] 40 KB
  __shared__ ushort convS[4096];           // [t_local(128)][f(32)] 8 KB
  __shared__ float pa_s[160];
  __shared__ float cw_s[FDIM * 33];
  __shared__ int ready_a[2], ready_b[2], done_c[2], conv_done;

  const int tid  = threadIdx.x;
  const int b    = blockIdx.y;
  const int t0b  = blockIdx.x * 128;
  const int wave = tid >> 6, lane = tid & 63;

  if (tid == 0) {
    ready_a[0] = ready_a[1] = ready_b[0] = ready_b[1] = 0;
    done_c[0] = done_c[1] = 0;
    conv_done = 0;
  }
  if (tid >= 512 && tid < 512 + 158) {
    int gt = t0b - 15 + (tid - 512);
    pa_s[tid - 512] = (gt >= 0 && gt < TDIM) ? pa[b * TDIM + gt] : 0.f;
  }
  if (tid < 512)
    for (int id = tid; id < FDIM * KW; id += 512)
      cw_s[(id / KW) * 33 + (id % KW)] = convw[id];
  __syncthreads();   // the only barrier: flags zeroed, pa_s/cw_s staged

  if (wave >= 8) {
    // ---------------- producers ----------------
    const bool isA = (wave < 10);
    const int p = wave & 1;               // which half of the 128 rows
    const float* gbase = isA ? enc + ((size_t)(b * TDIM + t0b)) * EDIM : Wenc;
    ushort* lbase = tiles + (isA ? 0 : TILE);
    int* myready = isA ? ready_a : ready_b;

    // prologue: loads for tile 0 into registers
    floatx4 v[8];
    #pragma unroll
    for (int j = 0; j < 4; ++j) {
      int idx = j * 64 + lane;
      int row = p * 64 + (idx >> 2), c = idx & 3;
      const float* g = gbase + (size_t)row * EDIM + c * 8;
      v[2 * j]     = *(const floatx4*)g;
      v[2 * j + 1] = *(const floatx4*)(g + 4);
    }

    for (int kt = 0; kt < 16; ++kt) {
      const int s = kt & 1, i = kt >> 1;
      if (kt >= 2)
        while (ld_acq(&done_c[s]) < 8 * i) __builtin_amdgcn_s_sleep(1);
      ushort* slot = lbase + s * 2 * TILE;
      #pragma unroll
      for (int j = 0; j < 4; ++j) {
        int idx = j * 64 + lane;
        int row = p * 64 + (idx >> 2), c = idx & 3;
        *(short8*)&slot[row * LSTR + c * 8] = pack8(v[2 * j], v[2 * j + 1]);
      }
      __threadfence_block();
      if (lane == 0) add_rel(&myready[s]);
      if (kt < 15) {
        // early loads for tile kt+1: in flight during the next done_c wait
        // and the consumers' MFMA on tiles kt-1/kt (register-targeted, no
        // slot needed)
        #pragma unroll
        for (int j = 0; j < 4; ++j) {
          int idx = j * 64 + lane;
          int row = p * 64 + (idx >> 2), c = idx & 3;
          const float* g = gbase + (size_t)row * EDIM + (kt + 1) * 32 + c * 8;
          v[2 * j]     = *(const floatx4*)g;
          v[2 * j + 1] = *(const floatx4*)(g + 4);
        }
      }
    }
    return;
  }

  // ---------------- consumers (waves 0-7) ----------------
  const int lc = lane & 15, lq = lane >> 4;

  // location conv -> convS (tid<512: tl spans all 128 rows)
  {
    const int tl = tid >> 2, fg = tid & 3;
    float cv[8];
    #pragma unroll
    for (int n = 0; n < 8; ++n) {
      int f = fg * 8 + n;
      float s = 0.f;
      #pragma unroll
      for (int k = 0; k < KW; ++k) s += pa_s[tl + k] * cw_s[f * 33 + k];
      cv[n] = s;
    }
    *(short8*)&convS[tl * 32 + fg * 8] =
        pack8((floatx4){cv[0], cv[1], cv[2], cv[3]},
              (floatx4){cv[4], cv[5], cv[6], cv[7]});
  }
  __threadfence_block();
  if (lane == 0) add_rel(&conv_done);

  floatx4 acc[8];
  #pragma unroll
  for (int aT = 0; aT < 8; ++aT) acc[aT] = (floatx4){0.f, 0.f, 0.f, 0.f};

  for (int kt = 0; kt < 16; ++kt) {
    const int s = kt & 1, i = kt >> 1;
    const int need = 2 * (i + 1);   // 2 producer waves per operand per tile
    while (ld_acq(&ready_a[s]) < need || ld_acq(&ready_b[s]) < need)
      __builtin_amdgcn_s_sleep(1);
    const ushort* As_ = tiles + s * 2 * TILE;
    const ushort* Bs_ = As_ + TILE;
    short8 af = *(const short8*)&As_[(wave * 16 + lc) * LSTR + lq * 8];
    #pragma unroll
    for (int aT = 0; aT < 8; ++aT) {
      short8 bf = *(const short8*)&Bs_[(aT * 16 + lc) * LSTR + lq * 8];
      acc[aT] = __builtin_amdgcn_mfma_f32_16x16x32_bf16(af, bf, acc[aT], 0, 0, 0);
    }
    if (lane == 0) add_rel(&done_c[s]);
  }

  // loc round: A = convS (needs all waves' conv writes), B = Wloc (global)
  while (ld_acq(&conv_done) < 8) __builtin_amdgcn_s_sleep(1);
  {
    short8 afl = *(const short8*)&convS[(wave * 16 + lc) * 32 + lq * 8];
    #pragma unroll
    for (int aT = 0; aT < 8; ++aT) {
      const float* g = Wloc + (size_t)(aT * 16 + lc) * FDIM + lq * 8;
      short8 bfl = pack8(*(const floatx4*)g, *(const floatx4*)(g + 4));
      acc[aT] = __builtin_amdgcn_mfma_f32_16x16x32_bf16(afl, bfl, acc[aT], 0, 0, 0);
    }
  }

  // epilogue (within-wave): e[t] = sum_a tanh(x + dp)*We + be
  const float be0 = be[0];
  float dpv[8], wev[8];
  #pragma unroll
  for (int aT = 0; aT < 8; ++aT) {
    int a = aT * 16 + lc;
    dpv[aT] = dec_p[b * ADIM + a];
    wev[aT] = We[a];
  }
  {
    float es[4] = {0.f, 0.f, 0.f, 0.f};
    #pragma unroll
    for (int aT = 0; aT < 8; ++aT)
      #pragma unroll
      for (int i = 0; i < 4; ++i)
        es[i] += fast_tanh(acc[aT][i] + dpv[aT]) * wev[aT];
    #pragma unroll
    for (int m = 1; m < 16; m <<= 1)
      #pragma unroll
      for (int i = 0; i < 4; ++i) es[i] += __shfl_xor(es[i], m, 64);
    if (lc == 0) {
      floatx4 ev = {es[0] + be0, es[1] + be0, es[2] + be0, es[3] + be0};
      *(floatx4*)&energ[(size_t)b * TDIM + t0b + wave * 16 + lq * 4] = ev;
    }
  }
}

// ---- fused softmax + context: grid (4 e-chunks of 128, B), 256 thr --------
__global__ __launch_bounds__(256)
void softmax_context_kernel(const float* __restrict__ enc,
                            const float* __restrict__ energ,
                            float* __restrict__ attn,
                            float* __restrict__ ctx) {
  __shared__ float aw[TDIM];
  __shared__ float redm[4];
  __shared__ float reds[4];
  __shared__ float red2[128];
  const int b = blockIdx.y, ex = blockIdx.x, tid = threadIdx.x;
  const float* row = energ + (size_t)b * TDIM;
  float x0 = row[tid], x1 = row[tid + 256];
  float m = fmaxf(x0, x1);
  #pragma unroll
  for (int off = 32; off; off >>= 1) m = fmaxf(m, __shfl_xor(m, off, 64));
  int wid = tid >> 6, lane = tid & 63;
  if (lane == 0) redm[wid] = m;
  __syncthreads();
  m = fmaxf(fmaxf(redm[0], redm[1]), fmaxf(redm[2], redm[3]));
  float e0 = __expf(x0 - m), e1 = __expf(x1 - m);
  float s = e0 + e1;
  #pragma unroll
  for (int off = 32; off; off >>= 1) s += __shfl_xor(s, off, 64);
  if (lane == 0) reds[wid] = s;
  __syncthreads();
  s = reds[0] + reds[1] + reds[2] + reds[3];
  float inv = 1.0f / s;
  float w0 = e0 * inv, w1 = e1 * inv;
  aw[tid] = w0; aw[tid + 256] = w1;
  if (ex == 0) {
    attn[(size_t)b * TDIM + tid] = w0;
    attn[(size_t)b * TDIM + tid + 256] = w1;
  }
  __syncthreads();
  const int j = tid & 127, h = tid >> 7;
  const float* ep = enc + ((size_t)(b * TDIM + h * 256)) * EDIM + ex * 128 + j;
  float acc = 0.f;
  #pragma unroll 16
  for (int t = 0; t < 256; ++t) acc += aw[h * 256 + t] * ep[(size_t)t * EDIM];
  if (h == 1) red2[j] = acc;
  __syncthreads();
  if (h == 0) ctx[(size_t)b * EDIM + ex * 128 + j] = acc + red2[j];
}

// In-place fallback (energies stored in attn slice): grid (1, B)
__global__ __launch_bounds__(256)
void softmax_context_inplace_kernel(const float* __restrict__ enc,
                                    float* __restrict__ attn,
                                    float* __restrict__ ctx) {
  __shared__ float aw[TDIM];
  __shared__ float redm[4];
  __shared__ float reds[4];
  const int b = blockIdx.y, tid = threadIdx.x;
  float* row = attn + (size_t)b * TDIM;
  float x0 = row[tid], x1 = row[tid + 256];
  float m = fmaxf(x0, x1);
  #pragma unroll
  for (int off = 32; off; off >>= 1) m = fmaxf(m, __shfl_xor(m, off, 64));
  int wid = tid >> 6, lane = tid & 63;
  if (lane == 0) redm[wid] = m;
  __syncthreads();
  m = fmaxf(fmaxf(redm[0], redm[1]), fmaxf(redm[2], redm[3]));
  float e0 = __expf(x0 - m), e1 = __expf(x1 - m);
  float s = e0 + e1;
  #pragma unroll
  for (int off = 32; off; off >>= 1) s += __shfl_xor(s, off, 64);
  if (lane == 0) reds[wid] = s;
  __syncthreads();
  s = reds[0] + reds[1] + reds[2] + reds[3];
  float inv = 1.0f / s;
  float w0 = e0 * inv, w1 = e1 * inv;
  row[tid] = w0; row[tid + 256] = w1;
  aw[tid] = w0; aw[tid + 256] = w1;
  __syncthreads();
  const float* ep = enc + ((size_t)b * TDIM) * EDIM;
  float a0 = 0.f, a1 = 0.f;
  #pragma unroll 8
  for (int t = 0; t < TDIM; ++t) {
    float w = aw[t];
    a0 += w * ep[(size_t)t * EDIM + tid];
    a1 += w * ep[(size_t)t * EDIM + tid + 256];
  }
  ctx[(size_t)b * EDIM + tid] = a0;
  ctx[(size_t)b * EDIM + tid + 256] = a1;
}

}  // namespace

extern "C" void kernel_launch(void* const* d_in, const int* in_sizes, int n_in,
                              void* d_out, int out_size, void* d_ws, size_t ws_size,
                              hipStream_t stream) {
  const float* enc   = (const float*)d_in[0];
  const float* dec   = (const float*)d_in[1];
  const float* pa    = (const float*)d_in[2];
  const float* Wenc  = (const float*)d_in[3];
  const float* Wdec  = (const float*)d_in[4];
  const float* convw = (const float*)d_in[5];
  const float* Wloc  = (const float*)d_in[6];
  const float* We    = (const float*)d_in[7];
  const float* be    = (const float*)d_in[8];

  float* ctx  = (float*)d_out;                 // [B,E]
  float* attn = (float*)d_out + BATCH * EDIM;  // [B,T]

  float* dec_p = (float*)d_ws;                 // 64 KB
  float* energ = dec_p + BATCH * ADIM;         // 256 KB

  const size_t need = (size_t)(BATCH * ADIM + BATCH * TDIM) * sizeof(float);

  dim3 g1(BATCH, 4);
  dec_proj_kernel<<<g1, 256, 0, stream>>>(dec, Wdec, dec_p);

  dim3 g2(TDIM / 128, BATCH);
  if (ws_size >= need) {
    energies_kernel<<<g2, 768, 0, stream>>>(enc, Wenc, pa, convw, Wloc, We, be,
                                            dec_p, energ);
    dim3 g3(4, BATCH);
    softmax_context_kernel<<<g3, 256, 0, stream>>>(enc, energ, attn, ctx);
  } else {
    energies_kernel<<<g2, 768, 0, stream>>>(enc, Wenc, pa, convw, Wloc, We, be,
                                            dec_p, attn);
    dim3 g3(1, BATCH);
    softmax_context_inplace_kernel<<<g3, 256, 0, stream>>>(enc, attn, ctx);
  }
}

// Round 11
// 244.047 us; speedup vs baseline: 1.1470x; 1.0045x over previous
//
#include <hip/hip_runtime.h>
#include <hip/hip_bf16.h>
#include <math.h>

namespace {
constexpr int EDIM  = 512;
constexpr int DDIM  = 1024;
constexpr int ADIM  = 128;
constexpr int FDIM  = 32;
constexpr int KW    = 31;
constexpr int BATCH = 128;
constexpr int TDIM  = 512;

constexpr int LSTR = 40;     // LDS row stride in ushorts (80 B -> 2-way banks, free)
constexpr int TILE = 128 * LSTR;  // one operand tile (5120 ushorts)

typedef __attribute__((ext_vector_type(8))) short short8;
typedef __attribute__((ext_vector_type(4))) float floatx4;

__device__ __forceinline__ float fast_tanh(float x) {
  x = fminf(9.0f, fmaxf(-9.0f, x));
  float e = __expf(2.0f * x);
  return (e - 1.0f) / (e + 1.0f);
}

__device__ __forceinline__ ushort2 pack_bf16(float x, float y) {
  union { __hip_bfloat162 h; ushort2 u; } cv;
  cv.h = __float22bfloat162_rn(make_float2(x, y));
  return cv.u;
}

__device__ __forceinline__ short8 pack8(floatx4 a, floatx4 b) {
  union { ushort2 u[4]; short8 v; } o;
  o.u[0] = pack_bf16(a[0], a[1]); o.u[1] = pack_bf16(a[2], a[3]);
  o.u[2] = pack_bf16(b[0], b[1]); o.u[3] = pack_bf16(b[2], b[3]);
  return o.v;
}

__device__ __forceinline__ int ld_acq(int* p) {
  return __hip_atomic_load(p, __ATOMIC_ACQUIRE, __HIP_MEMORY_SCOPE_WORKGROUP);
}
__device__ __forceinline__ void add_rel(int* p) {
  __hip_atomic_fetch_add(p, 1, __ATOMIC_RELEASE, __HIP_MEMORY_SCOPE_WORKGROUP);
}

// dec_p[b,a] = sum_d dec[b,d] * Wdec[a,d]   grid (B, 4), 256 thr
__global__ __launch_bounds__(256)
void dec_proj_kernel(const float* __restrict__ dec,
                     const float* __restrict__ Wdec,
                     float* __restrict__ dec_p) {
  int b = blockIdx.x, az = blockIdx.y;
  int tid = threadIdx.x;
  int al = tid >> 3, seg = tid & 7;
  int a = az * 32 + al;
  const float* dv = dec + (size_t)b * DDIM;
  const float* wv = Wdec + (size_t)a * DDIM;
  float s = 0.f;
  #pragma unroll 8
  for (int it = 0; it < 32; ++it) {
    int d = it * 32 + seg * 4;
    float4 d4 = *(const float4*)(dv + d);
    float4 w4 = *(const float4*)(wv + d);
    s += d4.x * w4.x + d4.y * w4.y + d4.z * w4.z + d4.w * w4.w;
  }
  s += __shfl_xor(s, 1, 64);
  s += __shfl_xor(s, 2, 64);
  s += __shfl_xor(s, 4, 64);
  if (seg == 0) dec_p[b * ADIM + a] = s;
}

// ------- energies v11: producer-consumer, slow polls + vectorized conv -----
// R10 structure. R11 changes (from the spin-DS-saturation diagnosis):
// (a) polls sleep longer (consumer ~384 cyc, producer ~640 cyc) so the spin
//     loops stop eating the DS pipe (R10: ~7M poll ds_reads/dispatch,
//     SQ_LDS_BANK_CONFLICT 3.4e6);
// (b) conv loop interchanged with cw transposed to [k][f] so the 8 filters
//     read as two ds_read_b128 per tap: 496 -> 93 DS instr/lane.
__global__ __launch_bounds__(768)
void energies_kernel(const float* __restrict__ enc,     // [B,T,E] fp32
                     const float* __restrict__ Wenc,    // [A,E] fp32
                     const float* __restrict__ pa,      // [B,T]
                     const float* __restrict__ convw,   // [F,1,K]
                     const float* __restrict__ Wloc,    // [A,F]
                     const float* __restrict__ We,      // [A]
                     const float* __restrict__ be,      // [1]
                     const float* __restrict__ dec_p,   // [B,A]
                     float* __restrict__ energ) {       // [B,T]
  __shared__ ushort tiles[2 * 2 * TILE];   // [slot(2)][A|B][128][LSTR] 40 KB
  __shared__ ushort convS[4096];           // [t_local(128)][f(32)] 8 KB
  __shared__ float pa_s[160];
  __shared__ float cw_t[KW * 32];          // transposed [k][f], ~4 KB
  __shared__ int ready_a[2], ready_b[2], done_c[2], conv_done;

  const int tid  = threadIdx.x;
  const int b    = blockIdx.y;
  const int t0b  = blockIdx.x * 128;
  const int wave = tid >> 6, lane = tid & 63;

  if (tid == 0) {
    ready_a[0] = ready_a[1] = ready_b[0] = ready_b[1] = 0;
    done_c[0] = done_c[1] = 0;
    conv_done = 0;
  }
  if (tid >= 512 && tid < 512 + 158) {
    int gt = t0b - 15 + (tid - 512);
    pa_s[tid - 512] = (gt >= 0 && gt < TDIM) ? pa[b * TDIM + gt] : 0.f;
  }
  if (tid < 512)
    for (int id = tid; id < FDIM * KW; id += 512)
      cw_t[(id % KW) * 32 + (id / KW)] = convw[id];   // [k][f]
  __syncthreads();   // the only barrier: flags zeroed, pa_s/cw_t staged

  if (wave >= 8) {
    // ---------------- producers ----------------
    const bool isA = (wave < 10);
    const int p = wave & 1;               // which half of the 128 rows
    const float* gbase = isA ? enc + ((size_t)(b * TDIM + t0b)) * EDIM : Wenc;
    ushort* lbase = tiles + (isA ? 0 : TILE);
    int* myready = isA ? ready_a : ready_b;

    // prologue: loads for tile 0 into registers
    floatx4 v[8];
    #pragma unroll
    for (int j = 0; j < 4; ++j) {
      int idx = j * 64 + lane;
      int row = p * 64 + (idx >> 2), c = idx & 3;
      const float* g = gbase + (size_t)row * EDIM + c * 8;
      v[2 * j]     = *(const floatx4*)g;
      v[2 * j + 1] = *(const floatx4*)(g + 4);
    }

    for (int kt = 0; kt < 16; ++kt) {
      const int s = kt & 1, i = kt >> 1;
      if (kt >= 2)
        while (ld_acq(&done_c[s]) < 8 * i) __builtin_amdgcn_s_sleep(10);
      ushort* slot = lbase + s * 2 * TILE;
      #pragma unroll
      for (int j = 0; j < 4; ++j) {
        int idx = j * 64 + lane;
        int row = p * 64 + (idx >> 2), c = idx & 3;
        *(short8*)&slot[row * LSTR + c * 8] = pack8(v[2 * j], v[2 * j + 1]);
      }
      __threadfence_block();
      if (lane == 0) add_rel(&myready[s]);
      if (kt < 15) {
        // early loads for tile kt+1: in flight during the next done_c wait
        #pragma unroll
        for (int j = 0; j < 4; ++j) {
          int idx = j * 64 + lane;
          int row = p * 64 + (idx >> 2), c = idx & 3;
          const float* g = gbase + (size_t)row * EDIM + (kt + 1) * 32 + c * 8;
          v[2 * j]     = *(const floatx4*)g;
          v[2 * j + 1] = *(const floatx4*)(g + 4);
        }
      }
    }
    return;
  }

  // ---------------- consumers (waves 0-7) ----------------
  const int lc = lane & 15, lq = lane >> 4;

  // location conv -> convS. Interchanged loops: per tap k, 1 pa read +
  // 2 ds_read_b128 of cw_t[k][fg*8..+8] (banks {0,8,16,24}, broadcast, free).
  {
    const int tl = tid >> 2, fg = tid & 3;
    float cv[8] = {0.f, 0.f, 0.f, 0.f, 0.f, 0.f, 0.f, 0.f};
    #pragma unroll
    for (int k = 0; k < KW; ++k) {
      float p = pa_s[tl + k];
      floatx4 c0 = *(const floatx4*)&cw_t[k * 32 + fg * 8];
      floatx4 c1 = *(const floatx4*)&cw_t[k * 32 + fg * 8 + 4];
      #pragma unroll
      for (int n = 0; n < 4; ++n) cv[n] += p * c0[n];
      #pragma unroll
      for (int n = 0; n < 4; ++n) cv[4 + n] += p * c1[n];
    }
    *(short8*)&convS[tl * 32 + fg * 8] =
        pack8((floatx4){cv[0], cv[1], cv[2], cv[3]},
              (floatx4){cv[4], cv[5], cv[6], cv[7]});
  }
  __threadfence_block();
  if (lane == 0) add_rel(&conv_done);

  floatx4 acc[8];
  #pragma unroll
  for (int aT = 0; aT < 8; ++aT) acc[aT] = (floatx4){0.f, 0.f, 0.f, 0.f};

  for (int kt = 0; kt < 16; ++kt) {
    const int s = kt & 1, i = kt >> 1;
    const int need = 2 * (i + 1);   // 2 producer waves per operand per tile
    while (ld_acq(&ready_a[s]) < need || ld_acq(&ready_b[s]) < need)
      __builtin_amdgcn_s_sleep(6);
    const ushort* As_ = tiles + s * 2 * TILE;
    const ushort* Bs_ = As_ + TILE;
    short8 af = *(const short8*)&As_[(wave * 16 + lc) * LSTR + lq * 8];
    #pragma unroll
    for (int aT = 0; aT < 8; ++aT) {
      short8 bf = *(const short8*)&Bs_[(aT * 16 + lc) * LSTR + lq * 8];
      acc[aT] = __builtin_amdgcn_mfma_f32_16x16x32_bf16(af, bf, acc[aT], 0, 0, 0);
    }
    if (lane == 0) add_rel(&done_c[s]);
  }

  // loc round: A = convS (needs all waves' conv writes), B = Wloc (global)
  while (ld_acq(&conv_done) < 8) __builtin_amdgcn_s_sleep(6);
  {
    short8 afl = *(const short8*)&convS[(wave * 16 + lc) * 32 + lq * 8];
    #pragma unroll
    for (int aT = 0; aT < 8; ++aT) {
      const float* g = Wloc + (size_t)(aT * 16 + lc) * FDIM + lq * 8;
      short8 bfl = pack8(*(const floatx4*)g, *(const floatx4*)(g + 4));
      acc[aT] = __builtin_amdgcn_mfma_f32_16x16x32_bf16(afl, bfl, acc[aT], 0, 0, 0);
    }
  }

  // epilogue (within-wave): e[t] = sum_a tanh(x + dp)*We + be
  const float be0 = be[0];
  float dpv[8], wev[8];
  #pragma unroll
  for (int aT = 0; aT < 8; ++aT) {
    int a = aT * 16 + lc;
    dpv[aT] = dec_p[b * ADIM + a];
    wev[aT] = We[a];
  }
  {
    float es[4] = {0.f, 0.f, 0.f, 0.f};
    #pragma unroll
    for (int aT = 0; aT < 8; ++aT)
      #pragma unroll
      for (int i = 0; i < 4; ++i)
        es[i] += fast_tanh(acc[aT][i] + dpv[aT]) * wev[aT];
    #pragma unroll
    for (int m = 1; m < 16; m <<= 1)
      #pragma unroll
      for (int i = 0; i < 4; ++i) es[i] += __shfl_xor(es[i], m, 64);
    if (lc == 0) {
      floatx4 ev = {es[0] + be0, es[1] + be0, es[2] + be0, es[3] + be0};
      *(floatx4*)&energ[(size_t)b * TDIM + t0b + wave * 16 + lq * 4] = ev;
    }
  }
}

// ---- fused softmax + context: grid (4 e-chunks of 128, B), 256 thr --------
__global__ __launch_bounds__(256)
void softmax_context_kernel(const float* __restrict__ enc,
                            const float* __restrict__ energ,
                            float* __restrict__ attn,
                            float* __restrict__ ctx) {
  __shared__ float aw[TDIM];
  __shared__ float redm[4];
  __shared__ float reds[4];
  __shared__ float red2[128];
  const int b = blockIdx.y, ex = blockIdx.x, tid = threadIdx.x;
  const float* row = energ + (size_t)b * TDIM;
  float x0 = row[tid], x1 = row[tid + 256];
  float m = fmaxf(x0, x1);
  #pragma unroll
  for (int off = 32; off; off >>= 1) m = fmaxf(m, __shfl_xor(m, off, 64));
  int wid = tid >> 6, lane = tid & 63;
  if (lane == 0) redm[wid] = m;
  __syncthreads();
  m = fmaxf(fmaxf(redm[0], redm[1]), fmaxf(redm[2], redm[3]));
  float e0 = __expf(x0 - m), e1 = __expf(x1 - m);
  float s = e0 + e1;
  #pragma unroll
  for (int off = 32; off; off >>= 1) s += __shfl_xor(s, off, 64);
  if (lane == 0) reds[wid] = s;
  __syncthreads();
  s = reds[0] + reds[1] + reds[2] + reds[3];
  float inv = 1.0f / s;
  float w0 = e0 * inv, w1 = e1 * inv;
  aw[tid] = w0; aw[tid + 256] = w1;
  if (ex == 0) {
    attn[(size_t)b * TDIM + tid] = w0;
    attn[(size_t)b * TDIM + tid + 256] = w1;
  }
  __syncthreads();
  const int j = tid & 127, h = tid >> 7;
  const float* ep = enc + ((size_t)(b * TDIM + h * 256)) * EDIM + ex * 128 + j;
  float acc = 0.f;
  #pragma unroll 16
  for (int t = 0; t < 256; ++t) acc += aw[h * 256 + t] * ep[(size_t)t * EDIM];
  if (h == 1) red2[j] = acc;
  __syncthreads();
  if (h == 0) ctx[(size_t)b * EDIM + ex * 128 + j] = acc + red2[j];
}

// In-place fallback (energies stored in attn slice): grid (1, B)
__global__ __launch_bounds__(256)
void softmax_context_inplace_kernel(const float* __restrict__ enc,
                                    float* __restrict__ attn,
                                    float* __restrict__ ctx) {
  __shared__ float aw[TDIM];
  __shared__ float redm[4];
  __shared__ float reds[4];
  const int b = blockIdx.y, tid = threadIdx.x;
  float* row = attn + (size_t)b * TDIM;
  float x0 = row[tid], x1 = row[tid + 256];
  float m = fmaxf(x0, x1);
  #pragma unroll
  for (int off = 32; off; off >>= 1) m = fmaxf(m, __shfl_xor(m, off, 64));
  int wid = tid >> 6, lane = tid & 63;
  if (lane == 0) redm[wid] = m;
  __syncthreads();
  m = fmaxf(fmaxf(redm[0], redm[1]), fmaxf(redm[2], redm[3]));
  float e0 = __expf(x0 - m), e1 = __expf(x1 - m);
  float s = e0 + e1;
  #pragma unroll
  for (int off = 32; off; off >>= 1) s += __shfl_xor(s, off, 64);
  if (lane == 0) reds[wid] = s;
  __syncthreads();
  s = reds[0] + reds[1] + reds[2] + reds[3];
  float inv = 1.0f / s;
  float w0 = e0 * inv, w1 = e1 * inv;
  row[tid] = w0; row[tid + 256] = w1;
  aw[tid] = w0; aw[tid + 256] = w1;
  __syncthreads();
  const float* ep = enc + ((size_t)b * TDIM) * EDIM;
  float a0 = 0.f, a1 = 0.f;
  #pragma unroll 8
  for (int t = 0; t < TDIM; ++t) {
    float w = aw[t];
    a0 += w * ep[(size_t)t * EDIM + tid];
    a1 += w * ep[(size_t)t * EDIM + tid + 256];
  }
  ctx[(size_t)b * EDIM + tid] = a0;
  ctx[(size_t)b * EDIM + tid + 256] = a1;
}

}  // namespace

extern "C" void kernel_launch(void* const* d_in, const int* in_sizes, int n_in,
                              void* d_out, int out_size, void* d_ws, size_t ws_size,
                              hipStream_t stream) {
  const float* enc   = (const float*)d_in[0];
  const float* dec   = (const float*)d_in[1];
  const float* pa    = (const float*)d_in[2];
  const float* Wenc  = (const float*)d_in[3];
  const float* Wdec  = (const float*)d_in[4];
  const float* convw = (const float*)d_in[5];
  const float* Wloc  = (const float*)d_in[6];
  const float* We    = (const float*)d_in[7];
  const float* be    = (const float*)d_in[8];

  float* ctx  = (float*)d_out;                 // [B,E]
  float* attn = (float*)d_out + BATCH * EDIM;  // [B,T]

  float* dec_p = (float*)d_ws;                 // 64 KB
  float* energ = dec_p + BATCH * ADIM;         // 256 KB

  const size_t need = (size_t)(BATCH * ADIM + BATCH * TDIM) * sizeof(float);

  dim3 g1(BATCH, 4);
  dec_proj_kernel<<<g1, 256, 0, stream>>>(dec, Wdec, dec_p);

  dim3 g2(TDIM / 128, BATCH);
  if (ws_size >= need) {
    energies_kernel<<<g2, 768, 0, stream>>>(enc, Wenc, pa, convw, Wloc, We, be,
                                            dec_p, energ);
    dim3 g3(4, BATCH);
    softmax_context_kernel<<<g3, 256, 0, stream>>>(enc, energ, attn, ctx);
  } else {
    energies_kernel<<<g2, 768, 0, stream>>>(enc, Wenc, pa, convw, Wloc, We, be,
                                            dec_p, attn);
    dim3 g3(1, BATCH);
    softmax_context_inplace_kernel<<<g3, 256, 0, stream>>>(enc, attn, ctx);
  }
}